// Round 8
// baseline (137.215 us; speedup 1.0000x reference)
//
#include <hip/hip_runtime.h>

#define BATCH 512
#define NPART 60
#define PFEAT 20
#define SFEAT 14
#define NVTX  5
#define HID   60
#define DE    20
#define DO    24
#define NCLS  2
#define SR    68          // LDS row stride in halves: 34 words -> 2-way banks max
#define RPB   30          // receivers per block (split = 2)

typedef _Float16 half8  __attribute__((ext_vector_type(8)));
typedef _Float16 half4v __attribute__((ext_vector_type(4)));
typedef __fp16   fp16x2 __attribute__((ext_vector_type(2)));
typedef float    f32x4  __attribute__((ext_vector_type(4)));

__device__ __forceinline__ half4v pkcvt4(f32x4 a) {
    fp16x2 lo = __builtin_amdgcn_cvt_pkrtz(a[0], a[1]);
    fp16x2 hi = __builtin_amdgcn_cvt_pkrtz(a[2], a[3]);
    half4v r;
    r[0] = (_Float16)lo[0]; r[1] = (_Float16)lo[1];
    r[2] = (_Float16)hi[0]; r[3] = (_Float16)hi[1];
    return r;
}
__device__ __forceinline__ half4v relu4(half4v a) {
#pragma unroll
    for (int j = 0; j < 4; ++j)
        a[j] = (a[j] > (_Float16)0.f) ? a[j] : (_Float16)0.f;
    return a;
}

// ---------------------------------------------------------------------------
// Prep kernel (unchanged from r6/r7): bias-as-K-row folding + carry columns.
// w3 tables double as A- or B-operands (identical reg layouts) — r7 swap.
// ---------------------------------------------------------------------------
__global__ __launch_bounds__(256) void prep_kernel(
    const float* __restrict__ x,
    const float* __restrict__ fr_w1, const float* __restrict__ fr_b1,
    const float* __restrict__ pv_w1,
    const float* __restrict__ fr_w2, const float* __restrict__ fr_b2,
    const float* __restrict__ fr_w3, const float* __restrict__ fr_b3,
    const float* __restrict__ pv_w2, const float* __restrict__ pv_b2,
    const float* __restrict__ pv_w3, const float* __restrict__ pv_b3,
    const float* __restrict__ fo_w1, const float* __restrict__ fo_b1,
    const float* __restrict__ fo_w2, const float* __restrict__ fo_b2,
    const float* __restrict__ fo_w3, const float* __restrict__ fo_b3,
    _Float16* __restrict__ frW2p, _Float16* __restrict__ frW3p16,
    _Float16* __restrict__ pvW2p, _Float16* __restrict__ pvW3p16,
    _Float16* __restrict__ foW1p, _Float16* __restrict__ foW2p16,
    _Float16* __restrict__ foW3p16,
    _Float16* __restrict__ frW1Ap, _Float16* __restrict__ frW1Bp,
    _Float16* __restrict__ pvW1Ap, _Float16* __restrict__ xp)
{
    if (blockIdx.x < 16) {
        int idx = blockIdx.x*256 + threadIdx.x;    // 0..4095
        {   // x32 A-tables [u<4][kk<2 in k][lane][8]: k = kk*32+q*8+j
            int j  = idx & 7;
            int L  = (idx >> 3) & 63;
            int kk = (idx >> 9) & 1;
            int u  = idx >> 10;
            int k  = kk*32 + (L >> 4)*8 + j;
            int n  = u*16 + (L & 15);
            float v2f = 0.f, v2p = 0.f, v1o = 0.f;
            if (k < HID && n < HID) {
                v2f = fr_w2[k*HID + n];
                v2p = pv_w2[k*HID + n];
                v1o = fo_w1[k*HID + n];
            } else if (k == HID) {          // bias row
                if (n < HID)      { v2f = fr_b2[n]; v2p = pv_b2[n]; v1o = fo_b1[n]; }
                else if (n == HID){ v2f = 1.f;      v2p = 1.f;      v1o = 1.f; }  // carry
            }
            frW2p[idx] = (_Float16)v2f;
            pvW2p[idx] = (_Float16)v2p;
            foW1p[idx] = (_Float16)v1o;
        }
        {   // x16 A-table, u<4: fo_w2; k = kt*16+q*4+j
            int j  = idx & 3;
            int L  = (idx >> 2) & 63;
            int kt = (idx >> 8) & 3;
            int u  = idx >> 10;
            int k  = kt*16 + (L >> 4)*4 + j;
            int n  = u*16 + (L & 15);
            float v = 0.f;
            if (k < HID && n < HID)        v = fo_w2[k*HID + n];
            else if (k == HID) {
                if (n < HID)       v = fo_b2[n];
                else if (n == HID) v = 1.f;                          // carry
            }
            foW2p16[idx] = (_Float16)v;
        }
        if (idx < 2048) {   // x16 tables, u<2: w3 (+ bias rows)
            {
                int j  = idx & 3;
                int L  = (idx >> 2) & 63;
                int kt = (idx >> 8) & 3;
                int u  = idx >> 10;
                int k  = kt*16 + (L >> 4)*4 + j;
                int n  = u*16 + (L & 15);
                float vf = 0.f, vp = 0.f, vo = 0.f;
                if (k < HID) {
                    if (n < DE) { vf = fr_w3[k*DE + n]; vp = pv_w3[k*DE + n]; }
                    if (n < DO)   vo = fo_w3[k*DO + n];
                } else if (k == HID) {      // bias row
                    if (n < DE) { vf = fr_b3[n]; vp = pv_b3[n]; }
                    if (n < DO)   vo = fo_b3[n];
                }
                frW3p16[idx] = (_Float16)vf;
                pvW3p16[idx] = (_Float16)vp;
                foW3p16[idx] = (_Float16)vo;
            }
            {   // layer-1 operand tables [u<4][lane][8]: k = q*8+j (<32)
                int j = idx & 7;
                int L = (idx >> 3) & 63;
                int u = idx >> 9;
                int k = (L >> 4)*8 + j;
                int n = u*16 + (L & 15);
                float va = 0.f, vb = 0.f, vpv = 0.f;
                if (k < PFEAT && n < HID) {
                    va  = fr_w1[k*HID + n];
                    vb  = fr_w1[(PFEAT + k)*HID + n];
                    vpv = pv_w1[k*HID + n];
                } else if (k == PFEAT) {    // bias row (A side only)
                    if (n < HID)       va = fr_b1[n];
                    else if (n == HID) va = 1.f;                     // carry in sFrA
                }
                frW1Ap[idx] = (_Float16)va;
                frW1Bp[idx] = (_Float16)vb;
                pvW1Ap[idx] = (_Float16)vpv;
            }
        }
    } else {
        // x transpose/convert: xp[b][q][p][8] fp16; k==PFEAT column = 1.0
        int idx = (blockIdx.x - 16)*256 + threadIdx.x;   // 0..BATCH*NPART*4-1
        if (idx < BATCH*NPART*4) {
            int p = idx % NPART;
            int t = idx / NPART;
            int q = t & 3;
            int b = t >> 2;
            half8 v;
#pragma unroll
            for (int j = 0; j < 8; ++j) {
                int k = q*8 + j;
                float f = 0.f;
                if (k < PFEAT)       f = x[((size_t)b*PFEAT + k)*NPART + p];
                else if (k == PFEAT) f = 1.f;                        // bias hook
                v[j] = (_Float16)f;
            }
            *(half8*)(xp + (size_t)idx*8) = v;   // idx == (b*4+q)*NPART + p
        }
    }
}

// ---------------------------------------------------------------------------
// Fused network kernel v11: v10 (40.7us) + receiver split (grid = BATCH*2,
// 30 receivers/block). Rationale: v10 is pipe-contention limited (VALU 48%,
// MFMA 33%, nothing saturated) and grid=512 pins residency at 2 blocks/CU;
// the r1 split failed when staging was fat/scalar (latency regime), but now
// duplication cost is ~10% and doubling resident blocks should push VALU
// toward saturation. LDS 25.4KB -> 4 blocks/CU at grid 1024. Partial Dsum
// to workspace; head kernel combines.
// ---------------------------------------------------------------------------
__global__ __launch_bounds__(512) void fused_kernel(
    const float* __restrict__ y,
    const float* __restrict__ pv_w1, const float* __restrict__ pv_b1,
    const half8*  __restrict__ frw2p, const half4v* __restrict__ frw3p16,
    const half8*  __restrict__ pvw2p, const half4v* __restrict__ pvw3p16,
    const half8*  __restrict__ fow1p, const half4v* __restrict__ fow2p16,
    const half4v* __restrict__ fow3p16,
    const half8*  __restrict__ frw1ap, const half8* __restrict__ frw1bp,
    const half8*  __restrict__ pvw1ap, const _Float16* __restrict__ xp,
    float* __restrict__ pdsum)        // [BATCH][2][DO]
{
    __shared__ __align__(16) _Float16 sFrA[32*SR];        // receiver rows; P2+: sCin
    __shared__ __align__(16) _Float16 sFrB[NPART*SR];     // all sender rows
    __shared__ __align__(16) _Float16 sPvA[32*SR];        // receiver rows
    __shared__ __align__(16) _Float16 sPvV[NVTX*64];
    __shared__ __align__(16) _Float16 sEpp[32*DE];
    __shared__ __align__(16) _Float16 sEpvP[NVTX*32*DE];
    __shared__ __align__(16) float    sDsum[2][DO];
    _Float16* sCin = sFrA;

    const f32x4 z4 = {0.f, 0.f, 0.f, 0.f};

    int bid  = blockIdx.x;
    int bb   = bid >> 1;
    int half = bid & 1;
    int base = half * RPB;
    int wv   = threadIdx.x >> 6;     // 0..7
    int lane = threadIdx.x & 63;
    int ml   = lane & 15;
    int q    = lane >> 4;

    // ================= P0: stage A (8 tiles / 8 waves) ======================
    {
        const half8* Wt; _Float16* Ot; int lr, row; bool ok;
        if (wv < 2)      { Wt = frw1ap; Ot = sFrA; lr = 16*wv + ml;     row = base + lr; ok = (lr < RPB); }
        else if (wv < 6) { Wt = frw1bp; Ot = sFrB; lr = 16*(wv-2) + ml; row = lr;        ok = (row < NPART); }
        else             { Wt = pvw1ap; Ot = sPvA; lr = 16*(wv-6) + ml; row = base + lr; ok = (lr < RPB); }
        int rr = ok ? row : 0;
        int strow = (wv >= 2 && wv < 6) ? rr : ((lr < RPB) ? lr : 0);
        half8 bX = *(const half8*)(xp + (((size_t)bb*4 + q)*NPART + rr)*8);
#pragma unroll
        for (int u = 0; u < 4; ++u) {
            half8 w8 = Wt[u*64 + lane];
            f32x4 acc = z4;
            acc = __builtin_amdgcn_mfma_f32_16x16x32_f16(w8, bX, acc, 0, 0, 0);
            if (ok)
                *(half4v*)(Ot + strow*SR + u*16 + 4*q) = pkcvt4(acc);
        }
        // pvV: 320 outputs, one per thread; col 60 = 1.0 (bias hook)
        for (int idx = threadIdx.x; idx < NVTX*64; idx += 512) {
            int v = idx >> 6;
            int h = idx & 63;
            float a;
            if (h < HID) {
                a = pv_b1[h];
#pragma unroll
                for (int f = 0; f < SFEAT; ++f)
                    a += y[((size_t)bb*SFEAT + f)*NVTX + v] * pv_w1[(PFEAT + f)*HID + h];
            } else {
                a = (h == HID) ? 1.f : 0.f;
            }
            sPvV[idx] = (_Float16)a;
        }
    }
    __syncthreads();

    // ================= P1a: fr-edge, lr = wv+8k local, swapped layer-3 ======
    {
        half8  w2r[8];
        half4v w3r[8];
#pragma unroll
        for (int t = 0; t < 8; ++t) w2r[t] = frw2p[t*64 + lane];
#pragma unroll
        for (int t = 0; t < 8; ++t) w3r[t] = frw3p16[t*64 + lane];
#pragma unroll
        for (int t = 0; t < 8; ++t) {
            asm volatile("" : "+v"(w2r[t]));
            asm volatile("" : "+v"(w3r[t]));
        }
        // chunk-3 output-row mask: edge = 48 + 4q + i valid iff 4q+i < 11
        float ok3[4];
#pragma unroll
        for (int i = 0; i < 4; ++i) ok3[i] = (4*q + i < 11) ? 1.f : 0.f;

        for (int lr = wv; lr < RPB; lr += 8) {
            int r = base + lr;                   // global receiver
            half8 u8k0 = *(const half8*)(sFrA + lr*SR + q*8);
            half8 u8k1 = *(const half8*)(sFrA + lr*SR + 32 + q*8);
            float s0 = 0.f, s1 = 0.f;

#pragma unroll
            for (int c = 0; c < 4; ++c) {
                int edge = 16*c + ml;
                bool eok = (edge < NPART-1);
                int sr = eok ? (edge + (edge >= r)) : 0;
                half8 bA0, bA1;
                {
                    half8 v8 = *(const half8*)(sFrB + sr*SR + q*8);
                    half8 s8 = u8k0 + v8;
#pragma unroll
                    for (int j = 0; j < 8; ++j)
                        s8[j] = (s8[j] > (_Float16)0.f) ? s8[j] : (_Float16)0.f;
                    bA0 = s8;
                    v8 = *(const half8*)(sFrB + sr*SR + 32 + q*8);
                    s8 = u8k1 + v8;
#pragma unroll
                    for (int j = 0; j < 8; ++j)
                        s8[j] = (s8[j] > (_Float16)0.f) ? s8[j] : (_Float16)0.f;
                    bA1 = s8;
                }
                half4v a3u[4];
#pragma unroll
                for (int u = 0; u < 4; ++u) {
                    f32x4 a = z4;
                    a = __builtin_amdgcn_mfma_f32_16x16x32_f16(w2r[u*2 + 0], bA0, a, 0, 0, 0);
                    a = __builtin_amdgcn_mfma_f32_16x16x32_f16(w2r[u*2 + 1], bA1, a, 0, 0, 0);
                    a3u[u] = relu4(pkcvt4(a));
                }
                // swapped: D[edge-in-chunk][feat]
                f32x4 e0 = z4, e1 = z4;
#pragma unroll
                for (int u = 0; u < 4; ++u) {
                    e0 = __builtin_amdgcn_mfma_f32_16x16x16f16(a3u[u], w3r[0*4 + u], e0, 0, 0, 0);
                    e1 = __builtin_amdgcn_mfma_f32_16x16x16f16(a3u[u], w3r[1*4 + u], e1, 0, 0, 0);
                }
                if (c < 3) {
#pragma unroll
                    for (int i = 0; i < 4; ++i) {
                        s0 += fmaxf(e0[i], 0.f);
                        s1 += fmaxf(e1[i], 0.f);
                    }
                } else {
#pragma unroll
                    for (int i = 0; i < 4; ++i) {
                        s0 = fmaf(fmaxf(e0[i], 0.f), ok3[i], s0);
                        s1 = fmaf(fmaxf(e1[i], 0.f), ok3[i], s1);
                    }
                }
            }
            // cross-q reduce (2 shuffles each) and scalar store
            s0 += __shfl_xor(s0, 16);
            s1 += __shfl_xor(s1, 16);
            s0 += __shfl_xor(s0, 32);
            s1 += __shfl_xor(s1, 32);
            if (q == 0) {
                sEpp[lr*DE + ml] = (_Float16)s0;          // feats 0..15
                if (ml < DE - 16)
                    sEpp[lr*DE + 16 + ml] = (_Float16)s1; // feats 16..19
            }
        }
    }

    // ================= P1b: pv groups, gv = wv-3 (waves 3-7), 2 tiles =======
    if (wv >= 3) {
        int gv = wv - 3;
        half8  w2r[8];
        half4v w3r[8];
#pragma unroll
        for (int t = 0; t < 8; ++t) w2r[t] = pvw2p[t*64 + lane];
#pragma unroll
        for (int t = 0; t < 8; ++t) w3r[t] = pvw3p16[t*64 + lane];
#pragma unroll
        for (int t = 0; t < 8; ++t) {
            asm volatile("" : "+v"(w2r[t]));
            asm volatile("" : "+v"(w3r[t]));
        }
        half8 u8k0 = *(const half8*)(sPvV + gv*64 + q*8);
        half8 u8k1 = *(const half8*)(sPvV + gv*64 + 32 + q*8);

        half8 bA[2][2];
#pragma unroll
        for (int tl = 0; tl < 2; ++tl) {
            int lp = 16*tl + ml;
            int sp = (lp < RPB) ? lp : 0;
#pragma unroll
            for (int kk = 0; kk < 2; ++kk) {
                half8 v8 = *(const half8*)(sPvA + sp*SR + kk*32 + q*8);
                half8 s8 = (kk ? u8k1 : u8k0) + v8;
#pragma unroll
                for (int j = 0; j < 8; ++j) {
                    _Float16 vj = s8[j];
                    s8[j] = (vj > (_Float16)0.f) ? vj : (_Float16)0.f;
                }
                bA[tl][kk] = s8;
            }
        }
        f32x4 acc3[2][2];
#pragma unroll
        for (int v = 0; v < 2; ++v)
#pragma unroll
            for (int tl = 0; tl < 2; ++tl) acc3[v][tl] = z4;
#pragma unroll
        for (int u = 0; u < 4; ++u) {
            half8 w0 = w2r[u*2 + 0];
            half8 w1 = w2r[u*2 + 1];
            half4v a3u[2];
#pragma unroll
            for (int tl = 0; tl < 2; ++tl) {
                f32x4 a = z4;
                a = __builtin_amdgcn_mfma_f32_16x16x32_f16(w0, bA[tl][0], a, 0, 0, 0);
                a = __builtin_amdgcn_mfma_f32_16x16x32_f16(w1, bA[tl][1], a, 0, 0, 0);
                a3u[tl] = relu4(pkcvt4(a));
            }
            half4v w3a = w3r[0*4 + u];
            half4v w3b = w3r[1*4 + u];
#pragma unroll
            for (int tl = 0; tl < 2; ++tl) {
                acc3[0][tl] = __builtin_amdgcn_mfma_f32_16x16x16f16(w3a, a3u[tl], acc3[0][tl], 0, 0, 0);
                acc3[1][tl] = __builtin_amdgcn_mfma_f32_16x16x16f16(w3b, a3u[tl], acc3[1][tl], 0, 0, 0);
            }
        }
#pragma unroll
        for (int v = 0; v < 2; ++v) {
            int col4 = v*16 + 4*q;
#pragma unroll
            for (int tl = 0; tl < 2; ++tl) {
                int lp = 16*tl + ml;
                if (lp < RPB && col4 < DE) {
                    half4v hv = relu4(pkcvt4(acc3[v][tl]));
                    *(half4v*)(sEpvP + (gv*32 + lp)*DE + col4) = hv;
                }
            }
        }
    }
    __syncthreads();

    // ================= P2: cin gather into sCin (aliases sFrA) ==============
    for (int idx = threadIdx.x; idx < RPB*64; idx += 512) {
        int lp = idx >> 6;
        int k  = idx & 63;
        _Float16 v;
        if (k < PFEAT) {
            v = xp[(((size_t)bb*4 + (k >> 3))*NPART + base + lp)*8 + (k & 7)];
        } else if (k < PFEAT + DE) {
            v = sEpp[lp*DE + (k - PFEAT)];
        } else if (k < PFEAT + 2*DE) {
            int c = k - PFEAT - DE;
            float s = 0.f;
#pragma unroll
            for (int g5 = 0; g5 < NVTX; ++g5)
                s += (float)sEpvP[(g5*32 + lp)*DE + c];
            v = (_Float16)s;
        } else {
            v = (k == HID) ? (_Float16)1.f : (_Float16)0.f;   // bias hook
        }
        sCin[lp*SR + k] = v;
    }
    __syncthreads();

    // ================= P3: object MLP (waves 0-1), swapped final layer ======
    if (wv < 2) {
        int lp = 16*wv + ml;
        int sp = (lp < RPB) ? lp : 0;
        half8 bC[2];
#pragma unroll
        for (int kk = 0; kk < 2; ++kk)
            bC[kk] = *(const half8*)(sCin + sp*SR + kk*32 + q*8);

        f32x4 acc1[4];
#pragma unroll
        for (int u = 0; u < 4; ++u) {
            acc1[u] = z4;
            acc1[u] = __builtin_amdgcn_mfma_f32_16x16x32_f16(fow1p[(u*2 + 0)*64 + lane], bC[0], acc1[u], 0, 0, 0);
            acc1[u] = __builtin_amdgcn_mfma_f32_16x16x32_f16(fow1p[(u*2 + 1)*64 + lane], bC[1], acc1[u], 0, 0, 0);
        }
        half4v a2[4];
#pragma unroll
        for (int u = 0; u < 4; ++u) a2[u] = relu4(pkcvt4(acc1[u]));

        f32x4 acc2[4];
#pragma unroll
        for (int u = 0; u < 4; ++u) {
            acc2[u] = z4;
#pragma unroll
            for (int kt = 0; kt < 4; ++kt)
                acc2[u] = __builtin_amdgcn_mfma_f32_16x16x16f16(fow2p16[(u*4 + kt)*64 + lane], a2[kt], acc2[u], 0, 0, 0);
        }
        half4v a3[4];
#pragma unroll
        for (int u = 0; u < 4; ++u) a3[u] = relu4(pkcvt4(acc2[u]));

        // swapped: D[p-in-tile][feat]; p_local = 16*wv + 4q + i, valid < RPB
        f32x4 e0 = z4, e1 = z4;
#pragma unroll
        for (int u = 0; u < 4; ++u) {
            e0 = __builtin_amdgcn_mfma_f32_16x16x16f16(a3[u], fow3p16[(0*4 + u)*64 + lane], e0, 0, 0, 0);
            e1 = __builtin_amdgcn_mfma_f32_16x16x16f16(a3[u], fow3p16[(1*4 + u)*64 + lane], e1, 0, 0, 0);
        }
        float s0 = 0.f, s1 = 0.f;
#pragma unroll
        for (int i = 0; i < 4; ++i) {
            float okp = (16*wv + 4*q + i < RPB) ? 1.f : 0.f;
            s0 = fmaf(fmaxf(e0[i], 0.f), okp, s0);
            s1 = fmaf(fmaxf(e1[i], 0.f), okp, s1);
        }
        s0 += __shfl_xor(s0, 16);
        s1 += __shfl_xor(s1, 16);
        s0 += __shfl_xor(s0, 32);
        s1 += __shfl_xor(s1, 32);
        if (q == 0) {
            sDsum[wv][ml] = s0;                   // feats 0..15
            if (ml < DO - 16)
                sDsum[wv][16 + ml] = s1;          // feats 16..23
        }
    }
    __syncthreads();

    // ================= partial Dsum -> workspace ============================
    if (wv == 0 && lane < DO) {
        pdsum[((size_t)bb*2 + half)*DO + lane] = sDsum[0][lane] + sDsum[1][lane];
    }
}

// ---------------------------------------------------------------------------
// Head kernel: combine the two receiver-half partials and apply fc.
// ---------------------------------------------------------------------------
__global__ __launch_bounds__(256) void head_kernel(
    const float* __restrict__ pdsum, const float* __restrict__ fcw,
    const float* __restrict__ fcb, float* __restrict__ out)
{
    int i = blockIdx.x*256 + threadIdx.x;       // 0..1023
    if (i >= BATCH*NCLS) return;
    int bb = i >> 1;
    int c  = i & 1;
    const float* p0 = pdsum + (size_t)bb*2*DO;
    float s = fcb[c];
#pragma unroll
    for (int d = 0; d < DO; ++d)
        s += (p0[d] + p0[DO + d]) * fcw[d*NCLS + c];
    out[i] = s;
}

// ---------------------------------------------------------------------------
extern "C" void kernel_launch(void* const* d_in, const int* in_sizes, int n_in,
                              void* d_out, int out_size, void* d_ws, size_t ws_size,
                              hipStream_t stream)
{
    const float* x     = (const float*)d_in[0];
    const float* y     = (const float*)d_in[1];
    const float* fr_w1 = (const float*)d_in[2];
    const float* fr_b1 = (const float*)d_in[3];
    const float* fr_w2 = (const float*)d_in[4];
    const float* fr_b2 = (const float*)d_in[5];
    const float* fr_w3 = (const float*)d_in[6];
    const float* fr_b3 = (const float*)d_in[7];
    const float* pv_w1 = (const float*)d_in[8];
    const float* pv_b1 = (const float*)d_in[9];
    const float* pv_w2 = (const float*)d_in[10];
    const float* pv_b2 = (const float*)d_in[11];
    const float* pv_w3 = (const float*)d_in[12];
    const float* pv_b3 = (const float*)d_in[13];
    const float* fo_w1 = (const float*)d_in[14];
    const float* fo_b1 = (const float*)d_in[15];
    const float* fo_w2 = (const float*)d_in[16];
    const float* fo_b2 = (const float*)d_in[17];
    const float* fo_w3 = (const float*)d_in[18];
    const float* fo_b3 = (const float*)d_in[19];
    const float* fc_w  = (const float*)d_in[20];
    const float* fc_b  = (const float*)d_in[21];
    float* out = (float*)d_out;

    char* wsb = (char*)d_ws;
    size_t off = 0;
    auto alloc = [&](size_t bytes) { char* p = wsb + off; off += (bytes + 255) & ~(size_t)255; return p; };

    _Float16* frW2p   = (_Float16*)alloc(4096*2);
    _Float16* frW3p16 = (_Float16*)alloc(2048*2);
    _Float16* pvW2p   = (_Float16*)alloc(4096*2);
    _Float16* pvW3p16 = (_Float16*)alloc(2048*2);
    _Float16* foW1p   = (_Float16*)alloc(4096*2);
    _Float16* foW2p16 = (_Float16*)alloc(4096*2);
    _Float16* foW3p16 = (_Float16*)alloc(2048*2);
    _Float16* frW1Ap  = (_Float16*)alloc(2048*2);
    _Float16* frW1Bp  = (_Float16*)alloc(2048*2);
    _Float16* pvW1Ap  = (_Float16*)alloc(2048*2);
    _Float16* xp      = (_Float16*)alloc((size_t)BATCH*NPART*32*2);
    float*    pdsum   = (float*)alloc((size_t)BATCH*2*DO*sizeof(float));

    int xblocks = (BATCH*NPART*4 + 255)/256;      // 480
    prep_kernel<<<16 + xblocks, 256, 0, stream>>>(
        x, fr_w1, fr_b1, pv_w1,
        fr_w2, fr_b2, fr_w3, fr_b3,
        pv_w2, pv_b2, pv_w3, pv_b3,
        fo_w1, fo_b1, fo_w2, fo_b2, fo_w3, fo_b3,
        frW2p, frW3p16, pvW2p, pvW3p16, foW1p, foW2p16, foW3p16,
        frW1Ap, frW1Bp, pvW1Ap, xp);

    fused_kernel<<<BATCH*2, 512, 0, stream>>>(
        y, pv_w1, pv_b1,
        (const half8*)frW2p, (const half4v*)frW3p16,
        (const half8*)pvW2p, (const half4v*)pvW3p16,
        (const half8*)foW1p, (const half4v*)foW2p16, (const half4v*)foW3p16,
        (const half8*)frW1Ap, (const half8*)frW1Bp,
        (const half8*)pvW1Ap, xp,
        pdsum);

    head_kernel<<<(BATCH*NCLS + 255)/256, 256, 0, stream>>>(pdsum, fc_w, fc_b, out);
}

// Round 9
// 134.418 us; speedup vs baseline: 1.0208x; 1.0208x over previous
//
#include <hip/hip_runtime.h>

#define BATCH 512
#define NPART 60
#define PFEAT 20
#define SFEAT 14
#define NVTX  5
#define HID   60
#define DE    20
#define DO    24
#define NCLS  2
#define SR    68          // LDS row stride in halves: 34 words -> 2-way banks max

typedef _Float16 half8  __attribute__((ext_vector_type(8)));
typedef _Float16 half4v __attribute__((ext_vector_type(4)));
typedef __fp16   fp16x2 __attribute__((ext_vector_type(2)));
typedef float    f32x4  __attribute__((ext_vector_type(4)));

__device__ __forceinline__ half4v pkcvt4(f32x4 a) {
    fp16x2 lo = __builtin_amdgcn_cvt_pkrtz(a[0], a[1]);
    fp16x2 hi = __builtin_amdgcn_cvt_pkrtz(a[2], a[3]);
    half4v r;
    r[0] = (_Float16)lo[0]; r[1] = (_Float16)lo[1];
    r[2] = (_Float16)hi[0]; r[3] = (_Float16)hi[1];
    return r;
}
__device__ __forceinline__ half4v relu4(half4v a) {
#pragma unroll
    for (int j = 0; j < 4; ++j)
        a[j] = (a[j] > (_Float16)0.f) ? a[j] : (_Float16)0.f;
    return a;
}

// ---------------------------------------------------------------------------
// Prep kernel: blocks 0-15 weight tables (bias-as-K-row + carry, r6/r7);
// blocks 16..495 xp transpose; blocks 496..1135 pvV precompute (moved out of
// the fused kernel's P0 — the 14-iter scalar loop now runs once here in the
// memory-bound prep instead of on the fused kernel's saturated issue port).
// ---------------------------------------------------------------------------
__global__ __launch_bounds__(256) void prep_kernel(
    const float* __restrict__ x, const float* __restrict__ y,
    const float* __restrict__ fr_w1, const float* __restrict__ fr_b1,
    const float* __restrict__ pv_w1, const float* __restrict__ pv_b1,
    const float* __restrict__ fr_w2, const float* __restrict__ fr_b2,
    const float* __restrict__ fr_w3, const float* __restrict__ fr_b3,
    const float* __restrict__ pv_w2, const float* __restrict__ pv_b2,
    const float* __restrict__ pv_w3, const float* __restrict__ pv_b3,
    const float* __restrict__ fo_w1, const float* __restrict__ fo_b1,
    const float* __restrict__ fo_w2, const float* __restrict__ fo_b2,
    const float* __restrict__ fo_w3, const float* __restrict__ fo_b3,
    _Float16* __restrict__ frW2p, _Float16* __restrict__ frW3p16,
    _Float16* __restrict__ pvW2p, _Float16* __restrict__ pvW3p16,
    _Float16* __restrict__ foW1p, _Float16* __restrict__ foW2p16,
    _Float16* __restrict__ foW3p16,
    _Float16* __restrict__ frW1Ap, _Float16* __restrict__ frW1Bp,
    _Float16* __restrict__ pvW1Ap, _Float16* __restrict__ xp,
    _Float16* __restrict__ pvvp)
{
    if (blockIdx.x < 16) {
        int idx = blockIdx.x*256 + threadIdx.x;    // 0..4095
        {   // x32 A-tables [u<4][kk<2 in k][lane][8]: k = kk*32+q*8+j
            int j  = idx & 7;
            int L  = (idx >> 3) & 63;
            int kk = (idx >> 9) & 1;
            int u  = idx >> 10;
            int k  = kk*32 + (L >> 4)*8 + j;
            int n  = u*16 + (L & 15);
            float v2f = 0.f, v2p = 0.f, v1o = 0.f;
            if (k < HID && n < HID) {
                v2f = fr_w2[k*HID + n];
                v2p = pv_w2[k*HID + n];
                v1o = fo_w1[k*HID + n];
            } else if (k == HID) {          // bias row
                if (n < HID)      { v2f = fr_b2[n]; v2p = pv_b2[n]; v1o = fo_b1[n]; }
                else if (n == HID){ v2f = 1.f;      v2p = 1.f;      v1o = 1.f; }  // carry
            }
            frW2p[idx] = (_Float16)v2f;
            pvW2p[idx] = (_Float16)v2p;
            foW1p[idx] = (_Float16)v1o;
        }
        {   // x16 A-table, u<4: fo_w2; k = kt*16+q*4+j
            int j  = idx & 3;
            int L  = (idx >> 2) & 63;
            int kt = (idx >> 8) & 3;
            int u  = idx >> 10;
            int k  = kt*16 + (L >> 4)*4 + j;
            int n  = u*16 + (L & 15);
            float v = 0.f;
            if (k < HID && n < HID)        v = fo_w2[k*HID + n];
            else if (k == HID) {
                if (n < HID)       v = fo_b2[n];
                else if (n == HID) v = 1.f;                          // carry
            }
            foW2p16[idx] = (_Float16)v;
        }
        if (idx < 2048) {   // x16 tables, u<2: w3 (+ bias rows)
            {
                int j  = idx & 3;
                int L  = (idx >> 2) & 63;
                int kt = (idx >> 8) & 3;
                int u  = idx >> 10;
                int k  = kt*16 + (L >> 4)*4 + j;
                int n  = u*16 + (L & 15);
                float vf = 0.f, vp = 0.f, vo = 0.f;
                if (k < HID) {
                    if (n < DE) { vf = fr_w3[k*DE + n]; vp = pv_w3[k*DE + n]; }
                    if (n < DO)   vo = fo_w3[k*DO + n];
                } else if (k == HID) {      // bias row
                    if (n < DE) { vf = fr_b3[n]; vp = pv_b3[n]; }
                    if (n < DO)   vo = fo_b3[n];
                }
                frW3p16[idx] = (_Float16)vf;
                pvW3p16[idx] = (_Float16)vp;
                foW3p16[idx] = (_Float16)vo;
            }
            {   // layer-1 operand tables [u<4][lane][8]: k = q*8+j (<32)
                int j = idx & 7;
                int L = (idx >> 3) & 63;
                int u = idx >> 9;
                int k = (L >> 4)*8 + j;
                int n = u*16 + (L & 15);
                float va = 0.f, vb = 0.f, vpv = 0.f;
                if (k < PFEAT && n < HID) {
                    va  = fr_w1[k*HID + n];
                    vb  = fr_w1[(PFEAT + k)*HID + n];
                    vpv = pv_w1[k*HID + n];
                } else if (k == PFEAT) {    // bias row (A side only)
                    if (n < HID)       va = fr_b1[n];
                    else if (n == HID) va = 1.f;                     // carry in sFrA
                }
                frW1Ap[idx] = (_Float16)va;
                frW1Bp[idx] = (_Float16)vb;
                pvW1Ap[idx] = (_Float16)vpv;
            }
        }
    } else if (blockIdx.x < 16 + 480) {
        // x transpose/convert: xp[b][q][p][8] fp16; k==PFEAT column = 1.0
        int idx = (blockIdx.x - 16)*256 + threadIdx.x;   // 0..BATCH*NPART*4-1
        if (idx < BATCH*NPART*4) {
            int p = idx % NPART;
            int t = idx / NPART;
            int q = t & 3;
            int b = t >> 2;
            half8 v;
#pragma unroll
            for (int j = 0; j < 8; ++j) {
                int k = q*8 + j;
                float f = 0.f;
                if (k < PFEAT)       f = x[((size_t)b*PFEAT + k)*NPART + p];
                else if (k == PFEAT) f = 1.f;                        // bias hook
                v[j] = (_Float16)f;
            }
            *(half8*)(xp + (size_t)idx*8) = v;   // idx == (b*4+q)*NPART + p
        }
    } else {
        // pvV precompute: pvvp[b][v][64] fp16; col 60 = 1.0 (bias hook)
        int idx = (blockIdx.x - (16 + 480))*256 + threadIdx.x;  // < 163840
        if (idx < BATCH*NVTX*64) {
            int h = idx & 63;
            int t = idx >> 6;          // b*NVTX + v
            int v = t % NVTX;
            int b = t / NVTX;
            float a;
            if (h < HID) {
                a = pv_b1[h];
#pragma unroll
                for (int f = 0; f < SFEAT; ++f)
                    a += y[((size_t)b*SFEAT + f)*NVTX + v] * pv_w1[(PFEAT + f)*HID + h];
            } else {
                a = (h == HID) ? 1.f : 0.f;
            }
            pvvp[idx] = (_Float16)a;
        }
    }
}

// ---------------------------------------------------------------------------
// Fused network kernel v12 (grid = 512, r7 base = 40.7us):
// Diagnosis after r8: per-CU throughput invariant to wave count at BOTH fat
// (r1) and lean (r8) operating points; VALU(50)+MFMA(33)+DS(~15) ~ 100% ->
// SIMD issue/execute bandwidth is the saturated shared resource. Only lever:
// total instruction count.
// Changes: (1) P1a/P3 edge/object sums moved onto the MFMA pipe — the
// swapped layer-3 D-fragment (row=4q+i,col=ml) is bit-identical to a
// B-fragment (k=4q+j,n=ml), so relu(P)->fp16 + mfma(ones,P,accS) contracts
// 16 edges/instruction with C-chaining; kills 16 f32 VALU/chunk + all
// cross-lane shuffles. (2) pvV precomputed in prep; P1b reads it from
// global (640B/block, L2-hot). (3) P1b moved to waves 4-7 (5 single-tile
// units each) — critical path 9.2 -> ~8.5 r-equivalents.
// ---------------------------------------------------------------------------
__global__ __launch_bounds__(512) void fused_kernel(
    const float* __restrict__ fcw, const float* __restrict__ fcb,
    const half8*  __restrict__ frw2p, const half4v* __restrict__ frw3p16,
    const half8*  __restrict__ pvw2p, const half4v* __restrict__ pvw3p16,
    const half8*  __restrict__ fow1p, const half4v* __restrict__ fow2p16,
    const half4v* __restrict__ fow3p16,
    const half8*  __restrict__ frw1ap, const half8* __restrict__ frw1bp,
    const half8*  __restrict__ pvw1ap, const _Float16* __restrict__ xp,
    const half8*  __restrict__ pvvp,
    float* __restrict__ out)
{
    __shared__ __align__(16) _Float16 sFrA[NPART*SR];     // P2+: aliased as sCin
    __shared__ __align__(16) _Float16 sFrB[NPART*SR];
    __shared__ __align__(16) _Float16 sPvA[NPART*SR];
    __shared__ __align__(16) _Float16 sEpp[NPART*DE];
    __shared__ __align__(16) _Float16 sEpvP[NVTX*NPART*DE];
    __shared__ __align__(16) float    sDsum[4][DO];
    _Float16* sCin = sFrA;

    const f32x4 z4 = {0.f, 0.f, 0.f, 0.f};

    int bb   = blockIdx.x;
    int wv   = threadIdx.x >> 6;     // 0..7
    int lane = threadIdx.x & 63;
    int ml   = lane & 15;
    int q    = lane >> 4;

    half4v onesA;
#pragma unroll
    for (int j = 0; j < 4; ++j) onesA[j] = (_Float16)1.f;

    // ================= P0: stage A (pure vector loads + MFMA) ===============
    {
        int tile = wv & 3;
        int row  = 16*tile + ml;
        int rr   = (row < NPART) ? row : 0;
        half8 bX = *(const half8*)(xp + (((size_t)bb*4 + q)*NPART + rr)*8);
#pragma unroll
        for (int task = 0; task < 2; ++task) {
            const half8* Wt; _Float16* Ot;
            if (wv < 4) {
                if (task == 0) { Wt = frw1ap; Ot = sFrA; }
                else           { Wt = pvw1ap; Ot = sPvA; }
            } else {
                if (task == 1) break;
                Wt = frw1bp; Ot = sFrB;
            }
#pragma unroll
            for (int u = 0; u < 4; ++u) {
                half8 w8 = Wt[u*64 + lane];
                f32x4 acc = z4;
                acc = __builtin_amdgcn_mfma_f32_16x16x32_f16(w8, bX, acc, 0, 0, 0);
                if (row < NPART)
                    *(half4v*)(Ot + row*SR + u*16 + 4*q) = pkcvt4(acc);
            }
        }
    }
    __syncthreads();

    // ================= P1a: fr-edge, swapped layer-3 + ones-MFMA edge sum ===
    {
        half8  w2r[8];
        half4v w3r[8];
#pragma unroll
        for (int t = 0; t < 8; ++t) w2r[t] = frw2p[t*64 + lane];
#pragma unroll
        for (int t = 0; t < 8; ++t) w3r[t] = frw3p16[t*64 + lane];
#pragma unroll
        for (int t = 0; t < 8; ++t) {
            asm volatile("" : "+v"(w2r[t]));
            asm volatile("" : "+v"(w3r[t]));
        }
        // chunk-3 B-row mask: edge = 48 + 4q + j valid iff 4q+j < 11
        half4v m3;
#pragma unroll
        for (int j = 0; j < 4; ++j) m3[j] = (_Float16)((4*q + j < 11) ? 1.f : 0.f);

        for (int r = wv; r < NPART; r += 8) {
            half8 u8k0 = *(const half8*)(sFrA + r*SR + q*8);
            half8 u8k1 = *(const half8*)(sFrA + r*SR + 32 + q*8);
            f32x4 accS0 = z4, accS1 = z4;

#pragma unroll
            for (int c = 0; c < 4; ++c) {
                int edge = 16*c + ml;
                int sr = (edge < NPART-1) ? (edge + (edge >= r)) : 0;
                half8 bA0, bA1;
                {
                    half8 v8 = *(const half8*)(sFrB + sr*SR + q*8);
                    half8 s8 = u8k0 + v8;
#pragma unroll
                    for (int j = 0; j < 8; ++j)
                        s8[j] = (s8[j] > (_Float16)0.f) ? s8[j] : (_Float16)0.f;
                    bA0 = s8;
                    v8 = *(const half8*)(sFrB + sr*SR + 32 + q*8);
                    s8 = u8k1 + v8;
#pragma unroll
                    for (int j = 0; j < 8; ++j)
                        s8[j] = (s8[j] > (_Float16)0.f) ? s8[j] : (_Float16)0.f;
                    bA1 = s8;
                }
                half4v a3u[4];
#pragma unroll
                for (int u = 0; u < 4; ++u) {
                    f32x4 a = z4;
                    a = __builtin_amdgcn_mfma_f32_16x16x32_f16(w2r[u*2 + 0], bA0, a, 0, 0, 0);
                    a = __builtin_amdgcn_mfma_f32_16x16x32_f16(w2r[u*2 + 1], bA1, a, 0, 0, 0);
                    a3u[u] = relu4(pkcvt4(a));
                }
                // swapped: D[edge-in-chunk][feat]
                f32x4 e0 = z4, e1 = z4;
#pragma unroll
                for (int u = 0; u < 4; ++u) {
                    e0 = __builtin_amdgcn_mfma_f32_16x16x16f16(a3u[u], w3r[0*4 + u], e0, 0, 0, 0);
                    e1 = __builtin_amdgcn_mfma_f32_16x16x16f16(a3u[u], w3r[1*4 + u], e1, 0, 0, 0);
                }
                // relu -> fp16 B-fragment; ones-MFMA contracts the 16 edges
                half4v p0 = relu4(pkcvt4(e0));
                half4v p1 = relu4(pkcvt4(e1));
                if (c == 3) { p0 *= m3; p1 *= m3; }
                accS0 = __builtin_amdgcn_mfma_f32_16x16x16f16(onesA, p0, accS0, 0, 0, 0);
                accS1 = __builtin_amdgcn_mfma_f32_16x16x16f16(onesA, p1, accS1, 0, 0, 0);
            }
            // every lane now holds the full edge-sum for its feat col
            if (q == 0) {
                sEpp[r*DE + ml] = (_Float16)accS0[0];            // feats 0..15
                if (ml < DE - 16)
                    sEpp[r*DE + 16 + ml] = (_Float16)accS1[0];   // feats 16..19
            }
        }
    }

    // ================= P1b: pv units on waves 4-7 (5 single-tile units) =====
    if (wv >= 4) {
        half8  w2r[8];
        half4v w3r[8];
#pragma unroll
        for (int t = 0; t < 8; ++t) w2r[t] = pvw2p[t*64 + lane];
#pragma unroll
        for (int t = 0; t < 8; ++t) w3r[t] = pvw3p16[t*64 + lane];
#pragma unroll
        for (int t = 0; t < 8; ++t) {
            asm volatile("" : "+v"(w2r[t]));
            asm volatile("" : "+v"(w3r[t]));
        }
        for (int kunit = wv - 4; kunit < 20; kunit += 4) {
            int gv = kunit >> 2;
            int tl = kunit & 3;
            int p  = 16*tl + ml;
            int sp = (p < NPART) ? p : 0;
            const half8* pvvB = pvvp + ((size_t)bb*NVTX + gv)*8;
            half8 u8k0 = pvvB[q];
            half8 u8k1 = pvvB[4 + q];

            half8 bA[2];
#pragma unroll
            for (int kk = 0; kk < 2; ++kk) {
                half8 v8 = *(const half8*)(sPvA + sp*SR + kk*32 + q*8);
                half8 s8 = (kk ? u8k1 : u8k0) + v8;
#pragma unroll
                for (int j = 0; j < 8; ++j) {
                    _Float16 vj = s8[j];
                    s8[j] = (vj > (_Float16)0.f) ? vj : (_Float16)0.f;
                }
                bA[kk] = s8;
            }
            f32x4 acc3[2];
            acc3[0] = z4; acc3[1] = z4;
#pragma unroll
            for (int u = 0; u < 4; ++u) {
                f32x4 a = z4;
                a = __builtin_amdgcn_mfma_f32_16x16x32_f16(w2r[u*2 + 0], bA[0], a, 0, 0, 0);
                a = __builtin_amdgcn_mfma_f32_16x16x32_f16(w2r[u*2 + 1], bA[1], a, 0, 0, 0);
                half4v a3u = relu4(pkcvt4(a));
                acc3[0] = __builtin_amdgcn_mfma_f32_16x16x16f16(w3r[0*4 + u], a3u, acc3[0], 0, 0, 0);
                acc3[1] = __builtin_amdgcn_mfma_f32_16x16x16f16(w3r[1*4 + u], a3u, acc3[1], 0, 0, 0);
            }
#pragma unroll
            for (int v = 0; v < 2; ++v) {
                int col4 = v*16 + 4*q;
                if (p < NPART && col4 < DE) {
                    half4v hv = relu4(pkcvt4(acc3[v]));
                    *(half4v*)(sEpvP + (gv*NPART + p)*DE + col4) = hv;
                }
            }
        }
    }
    __syncthreads();

    // ================= P2: cin gather into sCin (aliases sFrA) ==============
    for (int idx = threadIdx.x; idx < NPART*64; idx += 512) {
        int p = idx >> 6;
        int k = idx & 63;
        _Float16 v;
        if (k < PFEAT) {
            v = xp[(((size_t)bb*4 + (k >> 3))*NPART + p)*8 + (k & 7)];
        } else if (k < PFEAT + DE) {
            v = sEpp[p*DE + (k - PFEAT)];
        } else if (k < PFEAT + 2*DE) {
            int c = k - PFEAT - DE;
            float s = 0.f;
#pragma unroll
            for (int g5 = 0; g5 < NVTX; ++g5)
                s += (float)sEpvP[(g5*NPART + p)*DE + c];
            v = (_Float16)s;
        } else {
            v = (k == HID) ? (_Float16)1.f : (_Float16)0.f;   // bias hook
        }
        sCin[p*SR + k] = v;
    }
    __syncthreads();

    // ================= P3: object MLP (waves 0-3), ones-MFMA object sum =====
    if (wv < 4) {
        int p = 16*wv + ml;
        int sp = (p < NPART) ? p : 0;
        half8 bC[2];
#pragma unroll
        for (int kk = 0; kk < 2; ++kk)
            bC[kk] = *(const half8*)(sCin + sp*SR + kk*32 + q*8);

        f32x4 acc1[4];
#pragma unroll
        for (int u = 0; u < 4; ++u) {
            acc1[u] = z4;
            acc1[u] = __builtin_amdgcn_mfma_f32_16x16x32_f16(fow1p[(u*2 + 0)*64 + lane], bC[0], acc1[u], 0, 0, 0);
            acc1[u] = __builtin_amdgcn_mfma_f32_16x16x32_f16(fow1p[(u*2 + 1)*64 + lane], bC[1], acc1[u], 0, 0, 0);
        }
        half4v a2[4];
#pragma unroll
        for (int u = 0; u < 4; ++u) a2[u] = relu4(pkcvt4(acc1[u]));

        f32x4 acc2[4];
#pragma unroll
        for (int u = 0; u < 4; ++u) {
            acc2[u] = z4;
#pragma unroll
            for (int kt = 0; kt < 4; ++kt)
                acc2[u] = __builtin_amdgcn_mfma_f32_16x16x16f16(fow2p16[(u*4 + kt)*64 + lane], a2[kt], acc2[u], 0, 0, 0);
        }
        half4v a3[4];
#pragma unroll
        for (int u = 0; u < 4; ++u) a3[u] = relu4(pkcvt4(acc2[u]));

        // swapped: D[p-in-tile][feat]
        f32x4 e0 = z4, e1 = z4;
#pragma unroll
        for (int u = 0; u < 4; ++u) {
            e0 = __builtin_amdgcn_mfma_f32_16x16x16f16(a3[u], fow3p16[(0*4 + u)*64 + lane], e0, 0, 0, 0);
            e1 = __builtin_amdgcn_mfma_f32_16x16x16f16(a3[u], fow3p16[(1*4 + u)*64 + lane], e1, 0, 0, 0);
        }
        half4v p0 = relu4(pkcvt4(e0));
        half4v p1 = relu4(pkcvt4(e1));
        // objects p = 16*wv + 4q + j; invalid only for wv==3, q==3
        if (wv == 3 && q == 3) {
#pragma unroll
            for (int j = 0; j < 4; ++j) { p0[j] = (_Float16)0.f; p1[j] = (_Float16)0.f; }
        }
        f32x4 accP0 = __builtin_amdgcn_mfma_f32_16x16x16f16(onesA, p0, z4, 0, 0, 0);
        f32x4 accP1 = __builtin_amdgcn_mfma_f32_16x16x16f16(onesA, p1, z4, 0, 0, 0);
        if (q == 0) {
            sDsum[wv][ml] = accP0[0];                 // feats 0..15
            if (ml < DO - 16)
                sDsum[wv][16 + ml] = accP1[0];        // feats 16..23
        }
    }
    __syncthreads();

    // ================= fc head (wave 0) =====================================
    if (wv == 0) {
        float tot = 0.f;
        if (lane < DO) {
#pragma unroll
            for (int w4 = 0; w4 < 4; ++w4) tot += sDsum[w4][lane];
        }
        float p0 = (lane < DO) ? tot * fcw[lane*NCLS + 0] : 0.f;
        float p1 = (lane < DO) ? tot * fcw[lane*NCLS + 1] : 0.f;
#pragma unroll
        for (int d = 1; d <= 16; d <<= 1) {
            p0 += __shfl_xor(p0, d);
            p1 += __shfl_xor(p1, d);
        }
        if (lane == 0) {
            out[bb*NCLS + 0] = p0 + fcb[0];
            out[bb*NCLS + 1] = p1 + fcb[1];
        }
    }
}

// ---------------------------------------------------------------------------
extern "C" void kernel_launch(void* const* d_in, const int* in_sizes, int n_in,
                              void* d_out, int out_size, void* d_ws, size_t ws_size,
                              hipStream_t stream)
{
    const float* x     = (const float*)d_in[0];
    const float* y     = (const float*)d_in[1];
    const float* fr_w1 = (const float*)d_in[2];
    const float* fr_b1 = (const float*)d_in[3];
    const float* fr_w2 = (const float*)d_in[4];
    const float* fr_b2 = (const float*)d_in[5];
    const float* fr_w3 = (const float*)d_in[6];
    const float* fr_b3 = (const float*)d_in[7];
    const float* pv_w1 = (const float*)d_in[8];
    const float* pv_b1 = (const float*)d_in[9];
    const float* pv_w2 = (const float*)d_in[10];
    const float* pv_b2 = (const float*)d_in[11];
    const float* pv_w3 = (const float*)d_in[12];
    const float* pv_b3 = (const float*)d_in[13];
    const float* fo_w1 = (const float*)d_in[14];
    const float* fo_b1 = (const float*)d_in[15];
    const float* fo_w2 = (const float*)d_in[16];
    const float* fo_b2 = (const float*)d_in[17];
    const float* fo_w3 = (const float*)d_in[18];
    const float* fo_b3 = (const float*)d_in[19];
    const float* fc_w  = (const float*)d_in[20];
    const float* fc_b  = (const float*)d_in[21];
    float* out = (float*)d_out;

    char* wsb = (char*)d_ws;
    size_t off = 0;
    auto alloc = [&](size_t bytes) { char* p = wsb + off; off += (bytes + 255) & ~(size_t)255; return p; };

    _Float16* frW2p   = (_Float16*)alloc(4096*2);
    _Float16* frW3p16 = (_Float16*)alloc(2048*2);
    _Float16* pvW2p   = (_Float16*)alloc(4096*2);
    _Float16* pvW3p16 = (_Float16*)alloc(2048*2);
    _Float16* foW1p   = (_Float16*)alloc(4096*2);
    _Float16* foW2p16 = (_Float16*)alloc(4096*2);
    _Float16* foW3p16 = (_Float16*)alloc(2048*2);
    _Float16* frW1Ap  = (_Float16*)alloc(2048*2);
    _Float16* frW1Bp  = (_Float16*)alloc(2048*2);
    _Float16* pvW1Ap  = (_Float16*)alloc(2048*2);
    _Float16* xp      = (_Float16*)alloc((size_t)BATCH*NPART*32*2);
    _Float16* pvvp    = (_Float16*)alloc((size_t)BATCH*NVTX*64*2);

    int xblocks  = (BATCH*NPART*4 + 255)/256;     // 480
    int pvblocks = (BATCH*NVTX*64 + 255)/256;     // 640
    prep_kernel<<<16 + xblocks + pvblocks, 256, 0, stream>>>(
        x, y, fr_w1, fr_b1, pv_w1, pv_b1,
        fr_w2, fr_b2, fr_w3, fr_b3,
        pv_w2, pv_b2, pv_w3, pv_b3,
        fo_w1, fo_b1, fo_w2, fo_b2, fo_w3, fo_b3,
        frW2p, frW3p16, pvW2p, pvW3p16, foW1p, foW2p16, foW3p16,
        frW1Ap, frW1Bp, pvW1Ap, xp, pvvp);

    fused_kernel<<<BATCH, 512, 0, stream>>>(
        fc_w, fc_b,
        (const half8*)frW2p, (const half4v*)frW3p16,
        (const half8*)pvW2p, (const half4v*)pvW3p16,
        (const half8*)foW1p, (const half4v*)foW2p16, (const half4v*)foW3p16,
        (const half8*)frW1Ap, (const half8*)frW1Bp,
        (const half8*)pvW1Ap, xp, (const half8*)pvvp,
        out);
}

// Round 10
// 129.107 us; speedup vs baseline: 1.0628x; 1.0411x over previous
//
#include <hip/hip_runtime.h>

#define BATCH 512
#define NPART 60
#define PFEAT 20
#define SFEAT 14
#define NVTX  5
#define HID   60
#define DE    20
#define DO    24
#define NCLS  2
#define SR    68          // LDS row stride in halves: 34 words -> 2-way banks max

typedef _Float16 half8  __attribute__((ext_vector_type(8)));
typedef _Float16 half4v __attribute__((ext_vector_type(4)));
typedef __fp16   fp16x2 __attribute__((ext_vector_type(2)));
typedef float    f32x4  __attribute__((ext_vector_type(4)));

__device__ __forceinline__ half4v pkcvt4(f32x4 a) {
    fp16x2 lo = __builtin_amdgcn_cvt_pkrtz(a[0], a[1]);
    fp16x2 hi = __builtin_amdgcn_cvt_pkrtz(a[2], a[3]);
    half4v r;
    r[0] = (_Float16)lo[0]; r[1] = (_Float16)lo[1];
    r[2] = (_Float16)hi[0]; r[3] = (_Float16)hi[1];
    return r;
}
__device__ __forceinline__ half4v relu4(half4v a) {
#pragma unroll
    for (int j = 0; j < 4; ++j)
        a[j] = (a[j] > (_Float16)0.f) ? a[j] : (_Float16)0.f;
    return a;
}
// cvt two f32x4 accs into one relu'd half8 (k-order: 4 from a, then 4 from b)
__device__ __forceinline__ half8 cvtrelu8(f32x4 a, f32x4 b) {
    fp16x2 c0 = __builtin_amdgcn_cvt_pkrtz(a[0], a[1]);
    fp16x2 c1 = __builtin_amdgcn_cvt_pkrtz(a[2], a[3]);
    fp16x2 c2 = __builtin_amdgcn_cvt_pkrtz(b[0], b[1]);
    fp16x2 c3 = __builtin_amdgcn_cvt_pkrtz(b[2], b[3]);
    half8 r;
    r[0] = (_Float16)c0[0]; r[1] = (_Float16)c0[1];
    r[2] = (_Float16)c1[0]; r[3] = (_Float16)c1[1];
    r[4] = (_Float16)c2[0]; r[5] = (_Float16)c2[1];
    r[6] = (_Float16)c3[0]; r[7] = (_Float16)c3[1];
#pragma unroll
    for (int j = 0; j < 8; ++j)
        r[j] = (r[j] > (_Float16)0.f) ? r[j] : (_Float16)0.f;
    return r;
}

// ---------------------------------------------------------------------------
// Prep kernel. New in r10: the x16 layer-3/fo_w2 tables are replaced by x32
// tables packed with the CONCAT permutation pi(pair,q,j) = pair*32 +
// (j<4 ? q*4+j : 16+q*4+(j-4)) — matching the k-order of two concatenated
// x16 fragments, so one mfma_16x16x32 replaces two mfma_16x16x16 with both
// operands permutation-consistent (dot products unchanged).
// ---------------------------------------------------------------------------
__global__ __launch_bounds__(256) void prep_kernel(
    const float* __restrict__ x, const float* __restrict__ y,
    const float* __restrict__ fr_w1, const float* __restrict__ fr_b1,
    const float* __restrict__ pv_w1, const float* __restrict__ pv_b1,
    const float* __restrict__ fr_w2, const float* __restrict__ fr_b2,
    const float* __restrict__ fr_w3, const float* __restrict__ fr_b3,
    const float* __restrict__ pv_w2, const float* __restrict__ pv_b2,
    const float* __restrict__ pv_w3, const float* __restrict__ pv_b3,
    const float* __restrict__ fo_w1, const float* __restrict__ fo_b1,
    const float* __restrict__ fo_w2, const float* __restrict__ fo_b2,
    const float* __restrict__ fo_w3, const float* __restrict__ fo_b3,
    _Float16* __restrict__ frW2p, _Float16* __restrict__ frW3x,
    _Float16* __restrict__ pvW2p, _Float16* __restrict__ pvW3x,
    _Float16* __restrict__ foW1p, _Float16* __restrict__ foW2x,
    _Float16* __restrict__ foW3x,
    _Float16* __restrict__ frW1Ap, _Float16* __restrict__ frW1Bp,
    _Float16* __restrict__ pvW1Ap, _Float16* __restrict__ xp,
    _Float16* __restrict__ pvvp)
{
    if (blockIdx.x < 16) {
        int idx = blockIdx.x*256 + threadIdx.x;    // 0..4095
        {   // x32 A-tables [u<4][kk<2 in k][lane][8]: k = kk*32+q*8+j
            int j  = idx & 7;
            int L  = (idx >> 3) & 63;
            int kk = (idx >> 9) & 1;
            int u  = idx >> 10;
            int k  = kk*32 + (L >> 4)*8 + j;
            int n  = u*16 + (L & 15);
            float v2f = 0.f, v2p = 0.f, v1o = 0.f;
            if (k < HID && n < HID) {
                v2f = fr_w2[k*HID + n];
                v2p = pv_w2[k*HID + n];
                v1o = fo_w1[k*HID + n];
            } else if (k == HID) {          // bias row
                if (n < HID)      { v2f = fr_b2[n]; v2p = pv_b2[n]; v1o = fo_b1[n]; }
                else if (n == HID){ v2f = 1.f;      v2p = 1.f;      v1o = 1.f; }  // carry
            }
            frW2p[idx] = (_Float16)v2f;
            pvW2p[idx] = (_Float16)v2p;
            foW1p[idx] = (_Float16)v1o;
        }
        {   // x32 PERMUTED fo_w2 table foW2x [u<4][pair<2][lane][8]
            int j    = idx & 7;
            int L    = (idx >> 3) & 63;
            int pair = (idx >> 9) & 1;
            int u    = idx >> 10;
            int qq   = L >> 4;
            int k    = pair*32 + ((j < 4) ? (qq*4 + j) : (16 + qq*4 + (j - 4)));
            int n    = u*16 + (L & 15);
            float v = 0.f;
            if (k < HID) { if (n < HID) v = fo_w2[k*HID + n]; }
            else if (k == HID) {
                if (n < HID)       v = fo_b2[n];
                else if (n == HID) v = 1.f;                          // carry
            }
            foW2x[idx] = (_Float16)v;
        }
        if (idx < 2048) {
            {   // x32 PERMUTED w3 tables [v2<2][pair<2][lane][8]
                int j    = idx & 7;
                int L    = (idx >> 3) & 63;
                int pair = (idx >> 9) & 1;
                int v2   = idx >> 10;
                int qq   = L >> 4;
                int k    = pair*32 + ((j < 4) ? (qq*4 + j) : (16 + qq*4 + (j - 4)));
                int n    = v2*16 + (L & 15);
                float vf = 0.f, vp = 0.f, vo = 0.f;
                if (k < HID) {
                    if (n < DE) { vf = fr_w3[k*DE + n]; vp = pv_w3[k*DE + n]; }
                    if (n < DO)   vo = fo_w3[k*DO + n];
                } else if (k == HID) {      // bias row
                    if (n < DE) { vf = fr_b3[n]; vp = pv_b3[n]; }
                    if (n < DO)   vo = fo_b3[n];
                }
                frW3x[idx] = (_Float16)vf;
                pvW3x[idx] = (_Float16)vp;
                foW3x[idx] = (_Float16)vo;
            }
            {   // layer-1 operand tables [u<4][lane][8]: k = q*8+j (<32)
                int j = idx & 7;
                int L = (idx >> 3) & 63;
                int u = idx >> 9;
                int k = (L >> 4)*8 + j;
                int n = u*16 + (L & 15);
                float va = 0.f, vb = 0.f, vpv = 0.f;
                if (k < PFEAT && n < HID) {
                    va  = fr_w1[k*HID + n];
                    vb  = fr_w1[(PFEAT + k)*HID + n];
                    vpv = pv_w1[k*HID + n];
                } else if (k == PFEAT) {    // bias row (A side only)
                    if (n < HID)       va = fr_b1[n];
                    else if (n == HID) va = 1.f;                     // carry in sFrA
                }
                frW1Ap[idx] = (_Float16)va;
                frW1Bp[idx] = (_Float16)vb;
                pvW1Ap[idx] = (_Float16)vpv;
            }
        }
    } else if (blockIdx.x < 16 + 480) {
        // x transpose/convert: xp[b][q][p][8] fp16; k==PFEAT column = 1.0
        int idx = (blockIdx.x - 16)*256 + threadIdx.x;   // 0..BATCH*NPART*4-1
        if (idx < BATCH*NPART*4) {
            int p = idx % NPART;
            int t = idx / NPART;
            int q = t & 3;
            int b = t >> 2;
            half8 v;
#pragma unroll
            for (int j = 0; j < 8; ++j) {
                int k = q*8 + j;
                float f = 0.f;
                if (k < PFEAT)       f = x[((size_t)b*PFEAT + k)*NPART + p];
                else if (k == PFEAT) f = 1.f;                        // bias hook
                v[j] = (_Float16)f;
            }
            *(half8*)(xp + (size_t)idx*8) = v;   // idx == (b*4+q)*NPART + p
        }
    } else {
        // pvV precompute: pvvp[b][v][64] fp16; col 60 = 1.0 (bias hook)
        int idx = (blockIdx.x - (16 + 480))*256 + threadIdx.x;  // < 163840
        if (idx < BATCH*NVTX*64) {
            int h = idx & 63;
            int t = idx >> 6;          // b*NVTX + v
            int v = t % NVTX;
            int b = t / NVTX;
            float a;
            if (h < HID) {
                a = pv_b1[h];
#pragma unroll
                for (int f = 0; f < SFEAT; ++f)
                    a += y[((size_t)b*SFEAT + f)*NVTX + v] * pv_w1[(PFEAT + f)*HID + h];
            } else {
                a = (h == HID) ? 1.f : 0.f;
            }
            pvvp[idx] = (_Float16)a;
        }
    }
}

// ---------------------------------------------------------------------------
// Fused network kernel v13 (r9 base 40.0us). Model refined by r9: VALU+MFMA
// contend for one issue port, combined busy ~80% -> only NET issue-slot
// removal pays. Cuts: (1) x32-permuted layer-3 / P3-layer-2 (halves those
// MFMA issues, same execute); (2) P1b loops all 5 vertices per wave with
// f32 register accumulation -> 1 store, P2's 5-way gather -> 1 read;
// (3) P1a writes Epp straight into sCin (row r of sFrA is dead after the
// owning wave's iter-start reads) — sEpp + P2 copy branch deleted;
// (4) sFrB pad row 60 = -30000 makes invalid edges self-zero through the
// relu chain (bias-carry killed too) — m3 mask + chunk-3 special case gone.
// ---------------------------------------------------------------------------
__global__ __launch_bounds__(512) void fused_kernel(
    const float* __restrict__ fcw, const float* __restrict__ fcb,
    const half8*  __restrict__ frw2p, const half8* __restrict__ frw3x,
    const half8*  __restrict__ pvw2p, const half8* __restrict__ pvw3x,
    const half8*  __restrict__ fow1p, const half8* __restrict__ fow2x,
    const half8*  __restrict__ fow3x,
    const half8*  __restrict__ frw1ap, const half8* __restrict__ frw1bp,
    const half8*  __restrict__ pvw1ap, const _Float16* __restrict__ xp,
    const half8*  __restrict__ pvvp,
    float* __restrict__ out)
{
    __shared__ __align__(16) _Float16 sFrA[NPART*SR];     // P2+: aliased as sCin
    __shared__ __align__(16) _Float16 sFrB[64*SR];        // rows 60..63 = pad
    __shared__ __align__(16) _Float16 sPvA[NPART*SR];
    __shared__ __align__(16) _Float16 sEpvP[NPART*DE];    // vertex-summed Epv
    __shared__ __align__(16) float    sDsum[4][DO];
    _Float16* sCin = sFrA;

    const f32x4 z4 = {0.f, 0.f, 0.f, 0.f};

    int bb   = blockIdx.x;
    int wv   = threadIdx.x >> 6;     // 0..7
    int lane = threadIdx.x & 63;
    int ml   = lane & 15;
    int q    = lane >> 4;

    half4v onesA;
#pragma unroll
    for (int j = 0; j < 4; ++j) onesA[j] = (_Float16)1.f;

    // ================= P0: stage A (pure vector loads + MFMA) ===============
    {
        int tile = wv & 3;
        int row  = 16*tile + ml;
        int rr   = (row < NPART) ? row : 0;
        half8 bX = *(const half8*)(xp + (((size_t)bb*4 + q)*NPART + rr)*8);
#pragma unroll
        for (int task = 0; task < 2; ++task) {
            const half8* Wt; _Float16* Ot;
            if (wv < 4) {
                if (task == 0) { Wt = frw1ap; Ot = sFrA; }
                else           { Wt = pvw1ap; Ot = sPvA; }
            } else {
                if (task == 1) break;
                Wt = frw1bp; Ot = sFrB;
            }
#pragma unroll
            for (int u = 0; u < 4; ++u) {
                half8 w8 = Wt[u*64 + lane];
                f32x4 acc = z4;
                acc = __builtin_amdgcn_mfma_f32_16x16x32_f16(w8, bX, acc, 0, 0, 0);
                if (row < NPART)
                    *(half4v*)(Ot + row*SR + u*16 + 4*q) = pkcvt4(acc);
            }
        }
        // pad rows 60..63 of sFrB: -30000 so relu(u + v_pad) == 0 everywhere
        // (kills the bias-carry too -> invalid edges contribute exact zeros)
        if (threadIdx.x >= 256) {
            int t = threadIdx.x - 256;
            sFrB[(60 + (t >> 6))*SR + (t & 63)] = (_Float16)(-30000.f);
        }
    }
    __syncthreads();

    // ================= P1a: fr-edge, x32 layer-3, Epp direct to sCin ========
    {
        half8 w2r[8];
        half8 w3x[4];
#pragma unroll
        for (int t = 0; t < 8; ++t) w2r[t] = frw2p[t*64 + lane];
#pragma unroll
        for (int t = 0; t < 4; ++t) w3x[t] = frw3x[t*64 + lane];
#pragma unroll
        for (int t = 0; t < 8; ++t) asm volatile("" : "+v"(w2r[t]));
#pragma unroll
        for (int t = 0; t < 4; ++t) asm volatile("" : "+v"(w3x[t]));

        for (int r = wv; r < NPART; r += 8) {
            half8 u8k0 = *(const half8*)(sFrA + r*SR + q*8);
            half8 u8k1 = *(const half8*)(sFrA + r*SR + 32 + q*8);
            f32x4 accS0 = z4, accS1 = z4;

#pragma unroll
            for (int c = 0; c < 4; ++c) {
                int edge = 16*c + ml;
                int sr = (edge < NPART-1) ? (edge + (edge >= r)) : 60;
                half8 bA0, bA1;
                {
                    half8 v8 = *(const half8*)(sFrB + sr*SR + q*8);
                    half8 s8 = u8k0 + v8;
#pragma unroll
                    for (int j = 0; j < 8; ++j)
                        s8[j] = (s8[j] > (_Float16)0.f) ? s8[j] : (_Float16)0.f;
                    bA0 = s8;
                    v8 = *(const half8*)(sFrB + sr*SR + 32 + q*8);
                    s8 = u8k1 + v8;
#pragma unroll
                    for (int j = 0; j < 8; ++j)
                        s8[j] = (s8[j] > (_Float16)0.f) ? s8[j] : (_Float16)0.f;
                    bA1 = s8;
                }
                f32x4 L0 = z4, L1 = z4, L2 = z4, L3 = z4;
                L0 = __builtin_amdgcn_mfma_f32_16x16x32_f16(w2r[0], bA0, L0, 0, 0, 0);
                L0 = __builtin_amdgcn_mfma_f32_16x16x32_f16(w2r[1], bA1, L0, 0, 0, 0);
                L1 = __builtin_amdgcn_mfma_f32_16x16x32_f16(w2r[2], bA0, L1, 0, 0, 0);
                L1 = __builtin_amdgcn_mfma_f32_16x16x32_f16(w2r[3], bA1, L1, 0, 0, 0);
                L2 = __builtin_amdgcn_mfma_f32_16x16x32_f16(w2r[4], bA0, L2, 0, 0, 0);
                L2 = __builtin_amdgcn_mfma_f32_16x16x32_f16(w2r[5], bA1, L2, 0, 0, 0);
                L3 = __builtin_amdgcn_mfma_f32_16x16x32_f16(w2r[6], bA0, L3, 0, 0, 0);
                L3 = __builtin_amdgcn_mfma_f32_16x16x32_f16(w2r[7], bA1, L3, 0, 0, 0);
                half8 a3p0 = cvtrelu8(L0, L1);
                half8 a3p1 = cvtrelu8(L2, L3);
                // swapped x32 layer-3: D[edge-in-chunk][feat]
                f32x4 e0 = z4, e1 = z4;
                e0 = __builtin_amdgcn_mfma_f32_16x16x32_f16(a3p0, w3x[0], e0, 0, 0, 0);
                e0 = __builtin_amdgcn_mfma_f32_16x16x32_f16(a3p1, w3x[1], e0, 0, 0, 0);
                e1 = __builtin_amdgcn_mfma_f32_16x16x32_f16(a3p0, w3x[2], e1, 0, 0, 0);
                e1 = __builtin_amdgcn_mfma_f32_16x16x32_f16(a3p1, w3x[3], e1, 0, 0, 0);
                half4v p0 = relu4(pkcvt4(e0));
                half4v p1 = relu4(pkcvt4(e1));
                accS0 = __builtin_amdgcn_mfma_f32_16x16x16f16(onesA, p0, accS0, 0, 0, 0);
                accS1 = __builtin_amdgcn_mfma_f32_16x16x16f16(onesA, p1, accS1, 0, 0, 0);
            }
            // Epp direct into sCin cols 20..39 (row r of sFrA is dead now)
            if (q == 0) {
                sCin[r*SR + PFEAT + ml] = (_Float16)accS0[0];
                if (ml < DE - 16)
                    sCin[r*SR + PFEAT + 16 + ml] = (_Float16)accS1[0];
            }
        }
    }

    // ================= P1b: waves 4-7 own p-tile tl, loop 5 vertices ========
    if (wv >= 4) {
        int tl = wv - 4;
        int p  = 16*tl + ml;
        int sp = (p < NPART) ? p : 0;
        half8 w2r[8];
        half8 w3x[4];
#pragma unroll
        for (int t = 0; t < 8; ++t) w2r[t] = pvw2p[t*64 + lane];
#pragma unroll
        for (int t = 0; t < 4; ++t) w3x[t] = pvw3x[t*64 + lane];
#pragma unroll
        for (int t = 0; t < 8; ++t) asm volatile("" : "+v"(w2r[t]));
#pragma unroll
        for (int t = 0; t < 4; ++t) asm volatile("" : "+v"(w3x[t]));

        f32x4 accf0 = z4, accf1 = z4;       // vertex-summed relu(E2), f32
        for (int gv = 0; gv < NVTX; ++gv) {
            const half8* pvvB = pvvp + ((size_t)bb*NVTX + gv)*8;
            half8 u8k0 = pvvB[q];
            half8 u8k1 = pvvB[4 + q];
            half8 bA0, bA1;
            {
                half8 v8 = *(const half8*)(sPvA + sp*SR + q*8);
                half8 s8 = u8k0 + v8;
#pragma unroll
                for (int j = 0; j < 8; ++j)
                    s8[j] = (s8[j] > (_Float16)0.f) ? s8[j] : (_Float16)0.f;
                bA0 = s8;
                v8 = *(const half8*)(sPvA + sp*SR + 32 + q*8);
                s8 = u8k1 + v8;
#pragma unroll
                for (int j = 0; j < 8; ++j)
                    s8[j] = (s8[j] > (_Float16)0.f) ? s8[j] : (_Float16)0.f;
                bA1 = s8;
            }
            f32x4 L0 = z4, L1 = z4, L2 = z4, L3 = z4;
            L0 = __builtin_amdgcn_mfma_f32_16x16x32_f16(w2r[0], bA0, L0, 0, 0, 0);
            L0 = __builtin_amdgcn_mfma_f32_16x16x32_f16(w2r[1], bA1, L0, 0, 0, 0);
            L1 = __builtin_amdgcn_mfma_f32_16x16x32_f16(w2r[2], bA0, L1, 0, 0, 0);
            L1 = __builtin_amdgcn_mfma_f32_16x16x32_f16(w2r[3], bA1, L1, 0, 0, 0);
            L2 = __builtin_amdgcn_mfma_f32_16x16x32_f16(w2r[4], bA0, L2, 0, 0, 0);
            L2 = __builtin_amdgcn_mfma_f32_16x16x32_f16(w2r[5], bA1, L2, 0, 0, 0);
            L3 = __builtin_amdgcn_mfma_f32_16x16x32_f16(w2r[6], bA0, L3, 0, 0, 0);
            L3 = __builtin_amdgcn_mfma_f32_16x16x32_f16(w2r[7], bA1, L3, 0, 0, 0);
            half8 a3p0 = cvtrelu8(L0, L1);
            half8 a3p1 = cvtrelu8(L2, L3);
            // non-swapped x32 layer-3: D[feat][p]
            f32x4 a30 = z4, a31 = z4;
            a30 = __builtin_amdgcn_mfma_f32_16x16x32_f16(w3x[0], a3p0, a30, 0, 0, 0);
            a30 = __builtin_amdgcn_mfma_f32_16x16x32_f16(w3x[1], a3p1, a30, 0, 0, 0);
            a31 = __builtin_amdgcn_mfma_f32_16x16x32_f16(w3x[2], a3p0, a31, 0, 0, 0);
            a31 = __builtin_amdgcn_mfma_f32_16x16x32_f16(w3x[3], a3p1, a31, 0, 0, 0);
#pragma unroll
            for (int i = 0; i < 4; ++i) {
                accf0[i] += fmaxf(a30[i], 0.f);
                accf1[i] += fmaxf(a31[i], 0.f);
            }
        }
        // single store: feats 4q..4q+3 (accf0), 16..19 (accf1, q==0 only)
        if (p < NPART) {
            *(half4v*)(sEpvP + p*DE + 4*q) = pkcvt4(accf0);
            if (q == 0)
                *(half4v*)(sEpvP + p*DE + 16) = pkcvt4(accf1);
        }
    }
    __syncthreads();

    // ================= P2: cin gather (cols 20..39 already written) =========
    for (int idx = threadIdx.x; idx < NPART*64; idx += 512) {
        int p = idx >> 6;
        int k = idx & 63;
        if (k >= PFEAT && k < PFEAT + DE) continue;       // Epp: done by P1a
        _Float16 v;
        if (k < PFEAT) {
            v = xp[(((size_t)bb*4 + (k >> 3))*NPART + p)*8 + (k & 7)];
        } else if (k < PFEAT + 2*DE) {
            v = sEpvP[p*DE + (k - PFEAT - DE)];
        } else {
            v = (k == HID) ? (_Float16)1.f : (_Float16)0.f;   // bias hook
        }
        sCin[p*SR + k] = v;
    }
    __syncthreads();

    // ================= P3: object MLP (waves 0-3), x32 layers 2+3 ===========
    if (wv < 4) {
        int p = 16*wv + ml;
        int sp = (p < NPART) ? p : 0;
        half8 bC[2];
#pragma unroll
        for (int kk = 0; kk < 2; ++kk)
            bC[kk] = *(const half8*)(sCin + sp*SR + kk*32 + q*8);

        f32x4 acc1[4];
#pragma unroll
        for (int u = 0; u < 4; ++u) {
            acc1[u] = z4;
            acc1[u] = __builtin_amdgcn_mfma_f32_16x16x32_f16(fow1p[(u*2 + 0)*64 + lane], bC[0], acc1[u], 0, 0, 0);
            acc1[u] = __builtin_amdgcn_mfma_f32_16x16x32_f16(fow1p[(u*2 + 1)*64 + lane], bC[1], acc1[u], 0, 0, 0);
        }
        half8 a2p0 = cvtrelu8(acc1[0], acc1[1]);
        half8 a2p1 = cvtrelu8(acc1[2], acc1[3]);

        f32x4 acc2[4];
#pragma unroll
        for (int u = 0; u < 4; ++u) {
            acc2[u] = z4;
            acc2[u] = __builtin_amdgcn_mfma_f32_16x16x32_f16(fow2x[(u*2 + 0)*64 + lane], a2p0, acc2[u], 0, 0, 0);
            acc2[u] = __builtin_amdgcn_mfma_f32_16x16x32_f16(fow2x[(u*2 + 1)*64 + lane], a2p1, acc2[u], 0, 0, 0);
        }
        half8 a3p0 = cvtrelu8(acc2[0], acc2[1]);
        half8 a3p1 = cvtrelu8(acc2[2], acc2[3]);

        // swapped x32: D[p-in-tile][feat]
        f32x4 e0 = z4, e1 = z4;
        e0 = __builtin_amdgcn_mfma_f32_16x16x32_f16(a3p0, fow3x[0*64 + lane], e0, 0, 0, 0);
        e0 = __builtin_amdgcn_mfma_f32_16x16x32_f16(a3p1, fow3x[1*64 + lane], e0, 0, 0, 0);
        e1 = __builtin_amdgcn_mfma_f32_16x16x32_f16(a3p0, fow3x[2*64 + lane], e1, 0, 0, 0);
        e1 = __builtin_amdgcn_mfma_f32_16x16x32_f16(a3p1, fow3x[3*64 + lane], e1, 0, 0, 0);
        half4v p0 = relu4(pkcvt4(e0));
        half4v p1 = relu4(pkcvt4(e1));
        // objects p = 16*wv + 4q + j; invalid only for wv==3, q==3
        if (wv == 3 && q == 3) {
#pragma unroll
            for (int j = 0; j < 4; ++j) { p0[j] = (_Float16)0.f; p1[j] = (_Float16)0.f; }
        }
        f32x4 accP0 = __builtin_amdgcn_mfma_f32_16x16x16f16(onesA, p0, z4, 0, 0, 0);
        f32x4 accP1 = __builtin_amdgcn_mfma_f32_16x16x16f16(onesA, p1, z4, 0, 0, 0);
        if (q == 0) {
            sDsum[wv][ml] = accP0[0];                 // feats 0..15
            if (ml < DO - 16)
                sDsum[wv][16 + ml] = accP1[0];        // feats 16..23
        }
    }
    __syncthreads();

    // ================= fc head (wave 0) =====================================
    if (wv == 0) {
        float tot = 0.f;
        if (lane < DO) {
#pragma unroll
            for (int w4 = 0; w4 < 4; ++w4) tot += sDsum[w4][lane];
        }
        float p0 = (lane < DO) ? tot * fcw[lane*NCLS + 0] : 0.f;
        float p1 = (lane < DO) ? tot * fcw[lane*NCLS + 1] : 0.f;
#pragma unroll
        for (int d = 1; d <= 16; d <<= 1) {
            p0 += __shfl_xor(p0, d);
            p1 += __shfl_xor(p1, d);
        }
        if (lane == 0) {
            out[bb*NCLS + 0] = p0 + fcb[0];
            out[bb*NCLS + 1] = p1 + fcb[1];
        }
    }
}

// ---------------------------------------------------------------------------
extern "C" void kernel_launch(void* const* d_in, const int* in_sizes, int n_in,
                              void* d_out, int out_size, void* d_ws, size_t ws_size,
                              hipStream_t stream)
{
    const float* x     = (const float*)d_in[0];
    const float* y     = (const float*)d_in[1];
    const float* fr_w1 = (const float*)d_in[2];
    const float* fr_b1 = (const float*)d_in[3];
    const float* fr_w2 = (const float*)d_in[4];
    const float* fr_b2 = (const float*)d_in[5];
    const float* fr_w3 = (const float*)d_in[6];
    const float* fr_b3 = (const float*)d_in[7];
    const float* pv_w1 = (const float*)d_in[8];
    const float* pv_b1 = (const float*)d_in[9];
    const float* pv_w2 = (const float*)d_in[10];
    const float* pv_b2 = (const float*)d_in[11];
    const float* pv_w3 = (const float*)d_in[12];
    const float* pv_b3 = (const float*)d_in[13];
    const float* fo_w1 = (const float*)d_in[14];
    const float* fo_b1 = (const float*)d_in[15];
    const float* fo_w2 = (const float*)d_in[16];
    const float* fo_b2 = (const float*)d_in[17];
    const float* fo_w3 = (const float*)d_in[18];
    const float* fo_b3 = (const float*)d_in[19];
    const float* fc_w  = (const float*)d_in[20];
    const float* fc_b  = (const float*)d_in[21];
    float* out = (float*)d_out;

    char* wsb = (char*)d_ws;
    size_t off = 0;
    auto alloc = [&](size_t bytes) { char* p = wsb + off; off += (bytes + 255) & ~(size_t)255; return p; };

    _Float16* frW2p   = (_Float16*)alloc(4096*2);
    _Float16* frW3x   = (_Float16*)alloc(2048*2);
    _Float16* pvW2p   = (_Float16*)alloc(4096*2);
    _Float16* pvW3x   = (_Float16*)alloc(2048*2);
    _Float16* foW1p   = (_Float16*)alloc(4096*2);
    _Float16* foW2x   = (_Float16*)alloc(4096*2);
    _Float16* foW3x   = (_Float16*)alloc(2048*2);
    _Float16* frW1Ap  = (_Float16*)alloc(2048*2);
    _Float16* frW1Bp  = (_Float16*)alloc(2048*2);
    _Float16* pvW1Ap  = (_Float16*)alloc(2048*2);
    _Float16* xp      = (_Float16*)alloc((size_t)BATCH*NPART*32*2);
    _Float16* pvvp    = (_Float16*)alloc((size_t)BATCH*NVTX*64*2);

    int xblocks  = (BATCH*NPART*4 + 255)/256;     // 480
    int pvblocks = (BATCH*NVTX*64 + 255)/256;     // 640
    prep_kernel<<<16 + xblocks + pvblocks, 256, 0, stream>>>(
        x, y, fr_w1, fr_b1, pv_w1, pv_b1,
        fr_w2, fr_b2, fr_w3, fr_b3,
        pv_w2, pv_b2, pv_w3, pv_b3,
        fo_w1, fo_b1, fo_w2, fo_b2, fo_w3, fo_b3,
        frW2p, frW3x, pvW2p, pvW3x, foW1p, foW2x, foW3x,
        frW1Ap, frW1Bp, pvW1Ap, xp, pvvp);

    fused_kernel<<<BATCH, 512, 0, stream>>>(
        fc_w, fc_b,
        (const half8*)frW2p, (const half8*)frW3x,
        (const half8*)pvW2p, (const half8*)pvW3x,
        (const half8*)foW1p, (const half8*)foW2x, (const half8*)foW3x,
        (const half8*)frW1Ap, (const half8*)frW1Bp,
        (const half8*)pvW1Ap, xp, (const half8*)pvvp,
        out);
}